// Round 5
// baseline (353.070 us; speedup 1.0000x reference)
//
#include <hip/hip_runtime.h>
#include <math.h>

#define N 8192
#define D 256
#define EPSF 1e-8f
#define NJS 8           // j-splits per row-panel
#define ROWS 64         // output rows per block (16 per wave)
#define JSPAN 1024      // cols per block (N/NJS)
#define NC 16           // 64-col chunks per block (JSPAN/64)

// ws float offsets
#define WS_SQ    0                      // [N] |x|^2
#define WS_RINV  (N)                    // [N] 1/max(||x||,1e-12)
#define WS_GMEAN (2*N)                  // [256]
#define WS_MAXN  (2*N+256)              // [1] max norm
#define WS_COLP  (2*N+512)              // [65536] column partials
#define WS_P0    (2*N+512+65536)        // deg[8N] pot[8N] sl[8N] st[8N] tv[40N] = 72N
#define WS_TIX   (WS_P0+72*N)           // [40N] ints
#define WS_EBF   (WS_TIX+40*N)          // [2M ushort] bf16 emb (4MB)
// total ~8.2 MB

typedef __attribute__((ext_vector_type(8))) short bf16x8;
typedef __attribute__((ext_vector_type(4))) float f32x4;

__device__ __forceinline__ unsigned short f2bf(float f) {
    unsigned u = __float_as_uint(f);
    u += 0x7fffu + ((u >> 16) & 1u);
    return (unsigned short)(u >> 16);
}

#define INS5(TV, TI, dpv, jv) do {                                              \
    if ((dpv) < (TV)[4]) {                                                      \
      bool _b3 = (dpv) < (TV)[3], _b2 = (dpv) < (TV)[2];                        \
      bool _b1 = (dpv) < (TV)[1], _b0 = (dpv) < (TV)[0];                        \
      (TV)[4] = _b3 ? (TV)[3] : (dpv); (TI)[4] = _b3 ? (TI)[3] : (jv);          \
      (TV)[3] = _b3 ? (_b2 ? (TV)[2] : (dpv)) : (TV)[3];                        \
      (TI)[3] = _b3 ? (_b2 ? (TI)[2] : (jv))  : (TI)[3];                        \
      (TV)[2] = _b2 ? (_b1 ? (TV)[1] : (dpv)) : (TV)[2];                        \
      (TI)[2] = _b2 ? (_b1 ? (TI)[1] : (jv))  : (TI)[2];                        \
      (TV)[1] = _b1 ? (_b0 ? (TV)[0] : (dpv)) : (TV)[1];                        \
      (TI)[1] = _b1 ? (_b0 ? (TI)[0] : (jv))  : (TI)[1];                        \
      (TV)[0] = _b0 ? (dpv) : (TV)[0]; (TI)[0] = _b0 ? (jv) : (TI)[0];          \
    }                                                                           \
  } while (0)

// fused: blocks [0,2048) row stats + bf16 cast; [2048,2304) column partials
__global__ void k_prep(const float* __restrict__ emb, float* __restrict__ ws,
                       unsigned short* __restrict__ ebf) {
    if (blockIdx.x < 2048) {
        int row = blockIdx.x * 4 + (threadIdx.x >> 6);
        int lane = threadIdx.x & 63;
        float4 v = *(const float4*)(emb + (size_t)row * D + lane * 4);
        ushort4 b;
        b.x = f2bf(v.x); b.y = f2bf(v.y); b.z = f2bf(v.z); b.w = f2bf(v.w);
        *(ushort4*)(ebf + (size_t)row * D + lane * 4) = b;
        float s = v.x * v.x + v.y * v.y + v.z * v.z + v.w * v.w;
#pragma unroll
        for (int mk = 32; mk >= 1; mk >>= 1) s += __shfl_xor(s, mk);
        if (lane == 0) {
            ws[WS_SQ + row] = s;
            ws[WS_RINV + row] = 1.0f / fmaxf(sqrtf(s), 1e-12f);
        }
    } else {
        int d = threadIdx.x;
        int b = blockIdx.x - 2048;
        float s = 0.f;
        for (int r = b * 32; r < b * 32 + 32; ++r) s += emb[(size_t)r * D + d];
        ws[WS_COLP + b * 256 + d] = s;
    }
}

// gmean + maxnorm
__global__ void k_colred(float* __restrict__ ws) {
    __shared__ float red[256];
    int d = threadIdx.x;
    float s = 0.f;
    for (int b = 0; b < 256; ++b) s += ws[WS_COLP + b * 256 + d];
    ws[WS_GMEAN + d] = s * (1.0f / N);
    float mx = 0.f;
    for (int i = d; i < N; i += 256) mx = fmaxf(mx, ws[WS_SQ + i]);
    red[d] = mx;
    __syncthreads();
#pragma unroll
    for (int st2 = 128; st2 >= 1; st2 >>= 1) {
        if (d < st2) red[d] = fmaxf(red[d], red[d + st2]);
        __syncthreads();
    }
    if (d == 0) ws[WS_MAXN] = sqrtf(red[0]);
}

#define MFMA_CHUNK(JW)                                                          \
  do {                                                                          \
    _Pragma("unroll")                                                           \
    for (int mf = 0; mf < 4; ++mf) acc[mf] = (f32x4){0.f, 0.f, 0.f, 0.f};       \
    _Pragma("unroll")                                                           \
    for (int ks = 0; ks < 8; ++ks) {                                            \
      bf16x8 afr[4];                                                            \
      _Pragma("unroll")                                                         \
      for (int mf = 0; mf < 4; ++mf)                                            \
        afr[mf] = *(const bf16x8*)(ebf + (size_t)((JW) + mf * 16 + lid) * D + ks * 32 + g * 8); \
      _Pragma("unroll")                                                         \
      for (int mf = 0; mf < 4; ++mf)                                            \
        acc[mf] = __builtin_amdgcn_mfma_f32_16x16x32_bf16(afr[mf], bfr[ks], acc[mf], 0, 0, 0); \
    }                                                                           \
  } while (0)

#define LOADSR(JW)                                                              \
  do { _Pragma("unroll")                                                        \
    for (int mf = 0; mf < 4; ++mf) {                                            \
      sqv[mf] = *(const f32x4*)(sq + (JW) + mf * 16 + g * 4);                   \
      rvv[mf] = *(const f32x4*)(rinv + (JW) + mf * 16 + g * 4);                 \
    } } while (0)

#define LOADADV(BUF, JW)                                                        \
  do { _Pragma("unroll")                                                        \
    for (int mf = 0; mf < 4; ++mf)                                              \
      BUF[mf] = __builtin_nontemporal_load((const f32x4*)(arow + (JW) + mf * 16)); } while (0)

#define EPI(JW, ADV)                                                            \
  do { _Pragma("unroll")                                                        \
    for (int mf = 0; mf < 4; ++mf) {                                            \
      _Pragma("unroll")                                                         \
      for (int e = 0; e < 4; ++e) {                                             \
        const float gv = acc[mf][e];                                            \
        const float a = ADV[mf][e];                                             \
        const int j = (JW) + mf * 16 + g * 4 + e;                               \
        deg += a;                                                               \
        pot = fmaf(a, gv, pot);                                                 \
        const float s = (gv * rvr) * (rvv[mf][e] * a);                          \
        const float ex = __expf(s);                                             \
        sl += ex;                                                               \
        st = fmaf(ex, s, st);                                                   \
        float dp = fmaf(-2.f, gv, sqv[mf][e]);                                  \
        dp = (j == r) ? 1e30f : dp;                                             \
        INS5(tv, tix, dp, j);                                                   \
      }                                                                         \
    } } while (0)

// Block = 64 rows x 1024 cols. Wave w owns rows row0+w*16..+16; ALL waves sweep
// the SAME j-chunks (identical afr/sq/rv addresses -> L1-shared; 32KB/chunk).
// adj double-buffered across chunk pairs. No LDS, no barriers.
__global__ __launch_bounds__(256, 2) void k_main(
    const float* __restrict__ adj,
    const unsigned short* __restrict__ ebf,
    const float* __restrict__ ws,
    float* __restrict__ pout,
    int* __restrict__ tixp)
{
    const int tid = threadIdx.x;
    const int w = tid >> 6;
    const int lane = tid & 63;
    const int lid = lane & 15;
    const int g = lane >> 4;
    const int panel = blockIdx.x >> 3;     // 128 panels
    const int js = blockIdx.x & 7;
    const int row0 = panel * ROWS;
    const int jbase = js * JSPAN;
    const int r = row0 + w * 16 + lid;     // this lane's output row

    const float* sq = ws + WS_SQ;
    const float* rinv = ws + WS_RINV;
    const float* arow = adj + (size_t)r * N + g * 4;

    // persistent B-fragments: row r, full K=256
    bf16x8 bfr[8];
#pragma unroll
    for (int ks = 0; ks < 8; ++ks)
        bfr[ks] = *(const bf16x8*)(ebf + (size_t)r * D + ks * 32 + g * 8);
    const float rvr = rinv[r];

    float deg = 0.f, pot = 0.f, sl = 0.f, st = 0.f;
    float tv[5]; int tix[5];
#pragma unroll
    for (int s2 = 0; s2 < 5; ++s2) { tv[s2] = 1e30f; tix[s2] = N; }

    f32x4 acc[4], sqv[4], rvv[4], advA[4], advB[4];

    LOADADV(advA, jbase);
#pragma unroll 1
    for (int cc = 0; cc < NC / 2; ++cc) {
        const int jw0 = jbase + cc * 128;
        const int jw1 = jw0 + 64;
        const int jwn = (cc < NC / 2 - 1) ? (jw1 + 64) : jbase;  // last: dummy reload
        LOADSR(jw0);
        MFMA_CHUNK(jw0);
        LOADADV(advB, jw1);
        EPI(jw0, advA);
        LOADSR(jw1);
        MFMA_CHUNK(jw1);
        LOADADV(advA, jwn);
        EPI(jw1, advB);
    }

    // reduce across the 4 k-group lanes sharing row r (xor 16, 32)
#pragma unroll
    for (int mk = 16; mk <= 32; mk <<= 1) {
        deg += __shfl_xor(deg, mk);
        pot += __shfl_xor(pot, mk);
        sl += __shfl_xor(sl, mk);
        st += __shfl_xor(st, mk);
        float od[5]; int oi[5];
#pragma unroll
        for (int s2 = 0; s2 < 5; ++s2) {
            od[s2] = __shfl_xor(tv[s2], mk);
            oi[s2] = __shfl_xor(tix[s2], mk);
        }
#pragma unroll
        for (int s2 = 0; s2 < 5; ++s2) INS5(tv, tix, od[s2], oi[s2]);
    }
    if (g == 0) {
        const int slot = js * N + r;
        pout[slot] = deg;
        pout[8 * N + slot] = pot;
        pout[16 * N + slot] = sl;
        pout[24 * N + slot] = st;
#pragma unroll
        for (int s2 = 0; s2 < 5; ++s2) {
            pout[32 * N + slot * 5 + s2] = tv[s2];
            tixp[slot * 5 + s2] = tix[s2];
        }
    }
}

__global__ void k_final(const float* __restrict__ emb, const float* __restrict__ ws,
                        const int* __restrict__ tixp, float* __restrict__ out) {
    int row = blockIdx.x * 4 + (threadIdx.x >> 6);
    int lane = threadIdx.x & 63;
    const float* p0 = ws + WS_P0;

    float dg = 0.f, pt = 0.f, ll = 0.f, tt = 0.f;
#pragma unroll
    for (int js = 0; js < NJS; ++js) {
        int slot = js * N + row;
        dg += p0[slot]; pt += p0[8 * N + slot];
        ll += p0[16 * N + slot]; tt += p0[24 * N + slot];
    }

    float cd[40]; int ci[40];
#pragma unroll
    for (int js = 0; js < NJS; ++js)
#pragma unroll
        for (int s = 0; s < 5; ++s) {
            int slot = js * N + row;
            cd[js * 5 + s] = p0[32 * N + slot * 5 + s];
            ci[js * 5 + s] = tixp[slot * 5 + s];
        }
    int nb[5];
    unsigned long long picked = 0ull;
#pragma unroll
    for (int sel = 0; sel < 5; ++sel) {
        float best = 1e31f; int bi = 0, bq = 0;
#pragma unroll
        for (int q = 0; q < 40; ++q) {
            bool ok = (((picked >> q) & 1ull) == 0ull) && (cd[q] < best);
            best = ok ? cd[q] : best;
            bi = ok ? ci[q] : bi;
            bq = ok ? q : bq;
        }
        picked |= (1ull << bq);
        nb[sel] = bi;
    }

    float4 e = *(const float4*)(emb + (size_t)row * D + lane * 4);
    float4 gm = *(const float4*)(ws + WS_GMEAN + lane * 4);
    float gx = e.x - gm.x, gy = e.y - gm.y, gz = e.z - gm.z, gw = e.w - gm.w;
    float gd = gx * gx + gy * gy + gz * gz + gw * gw;
    float ax = 0.f, ay = 0.f, az = 0.f, aw = 0.f;
#pragma unroll
    for (int t = 0; t < 5; ++t) {
        float4 nv = *(const float4*)(emb + (size_t)nb[t] * D + lane * 4);
        ax += nv.x; ay += nv.y; az += nv.z; aw += nv.w;
    }
    ax *= 0.2f; ay *= 0.2f; az *= 0.2f; aw *= 0.2f;
    float lx = e.x - ax, ly = e.y - ay, lz = e.z - az, lw = e.w - aw;
    float ld = lx * lx + ly * ly + lz * lz + lw * lw;
#pragma unroll
    for (int mk = 32; mk >= 1; mk >>= 1) {
        gd += __shfl_xor(gd, mk);
        ld += __shfl_xor(ld, mk);
    }
    if (lane == 0) {
        float sqv = ws[WS_SQ + row];
        float mn = ws[WS_MAXN];
        float ent = logf(ll) - tt / ll;
        out[row] = sqv - pt / (dg + EPSF);
        out[N + row] = (dg > 0.f) ? ent : 0.f;
        out[2 * N + row] = 0.6f * sqrtf(gd) + 0.4f * sqrtf(ld);
        out[3 * N + row] = 0.5f * (dg / (8191.0f + EPSF)) + 0.5f * (sqrtf(sqv) / (mn + EPSF));
    }
}

extern "C" void kernel_launch(void* const* d_in, const int* in_sizes, int n_in,
                              void* d_out, int out_size, void* d_ws, size_t ws_size,
                              hipStream_t stream) {
    const float* emb = (const float*)d_in[0];
    const float* adj = (const float*)d_in[1];
    float* out = (float*)d_out;
    float* ws = (float*)d_ws;
    unsigned short* ebf = (unsigned short*)(ws + WS_EBF);

    k_prep<<<2304, 256, 0, stream>>>(emb, ws, ebf);
    k_colred<<<1, 256, 0, stream>>>(ws);
    k_main<<<1024, 256, 0, stream>>>(adj, ebf, ws, ws + WS_P0, (int*)(ws + WS_TIX));
    k_final<<<N / 4, 256, 0, stream>>>(emb, ws, (const int*)(ws + WS_TIX), out);
}

// Round 7
// 252.071 us; speedup vs baseline: 1.4007x; 1.4007x over previous
//
#include <hip/hip_runtime.h>
#include <math.h>

#define N 8192
#define D 256
#define EPSF 1e-8f
#define NJS 4            // j-splits
#define ROWS 32          // out-rows per block
#define JSPAN 2048       // j-cols per block
#define NU 64            // units per block: 16 chunks x 4 K-slices

// ws float offsets
#define WS_SQ    0
#define WS_RINV  (N)
#define WS_GMEAN (2*N)
#define WS_MAXN  (2*N+256)
#define WS_COLP  (2*N+512)              // [65536]
#define WS_P0    (2*N+512+65536)        // deg[4N] pot[4N] sl[4N] st[4N] tv[20N] = 36N
#define WS_TIX   (WS_P0+36*N)           // [20N] ints
#define WS_EBF   (WS_TIX+20*N)          // [2M ushort] bf16 emb (4MB)

typedef __attribute__((ext_vector_type(8))) short bf16x8;
typedef __attribute__((ext_vector_type(4))) float f32x4;

__device__ __forceinline__ unsigned short f2bf(float f) {
    unsigned u = __float_as_uint(f);
    u += 0x7fffu + ((u >> 16) & 1u);
    return (unsigned short)(u >> 16);
}

#define INS5(TV, TI, dpv, jv) do {                                              \
    if ((dpv) < (TV)[4]) {                                                      \
      bool _b3 = (dpv) < (TV)[3], _b2 = (dpv) < (TV)[2];                        \
      bool _b1 = (dpv) < (TV)[1], _b0 = (dpv) < (TV)[0];                        \
      (TV)[4] = _b3 ? (TV)[3] : (dpv); (TI)[4] = _b3 ? (TI)[3] : (jv);          \
      (TV)[3] = _b3 ? (_b2 ? (TV)[2] : (dpv)) : (TV)[3];                        \
      (TI)[3] = _b3 ? (_b2 ? (TI)[2] : (jv))  : (TI)[3];                        \
      (TV)[2] = _b2 ? (_b1 ? (TV)[1] : (dpv)) : (TV)[2];                        \
      (TI)[2] = _b2 ? (_b1 ? (TI)[1] : (jv))  : (TI)[2];                        \
      (TV)[1] = _b1 ? (_b0 ? (TV)[0] : (dpv)) : (TV)[1];                        \
      (TI)[1] = _b1 ? (_b0 ? (TI)[0] : (jv))  : (TI)[1];                        \
      (TV)[0] = _b0 ? (dpv) : (TV)[0]; (TI)[0] = _b0 ? (jv) : (TI)[0];          \
    }                                                                           \
  } while (0)

__global__ void k_prep(const float* __restrict__ emb, float* __restrict__ ws,
                       unsigned short* __restrict__ ebf) {
    if (blockIdx.x < 2048) {
        int row = blockIdx.x * 4 + (threadIdx.x >> 6);
        int lane = threadIdx.x & 63;
        float4 v = *(const float4*)(emb + (size_t)row * D + lane * 4);
        ushort4 b;
        b.x = f2bf(v.x); b.y = f2bf(v.y); b.z = f2bf(v.z); b.w = f2bf(v.w);
        *(ushort4*)(ebf + (size_t)row * D + lane * 4) = b;
        float s = v.x * v.x + v.y * v.y + v.z * v.z + v.w * v.w;
#pragma unroll
        for (int mk = 32; mk >= 1; mk >>= 1) s += __shfl_xor(s, mk);
        if (lane == 0) {
            ws[WS_SQ + row] = s;
            ws[WS_RINV + row] = 1.0f / fmaxf(sqrtf(s), 1e-12f);
        }
    } else {
        int d = threadIdx.x;
        int b = blockIdx.x - 2048;
        float s = 0.f;
        for (int r = b * 32; r < b * 32 + 32; ++r) s += emb[(size_t)r * D + d];
        ws[WS_COLP + b * 256 + d] = s;
    }
}

__global__ void k_colred(float* __restrict__ ws) {
    __shared__ float red[256];
    int d = threadIdx.x;
    float s = 0.f;
    for (int b = 0; b < 256; ++b) s += ws[WS_COLP + b * 256 + d];
    ws[WS_GMEAN + d] = s * (1.0f / N);
    float mx = 0.f;
    for (int i = d; i < N; i += 256) mx = fmaxf(mx, ws[WS_SQ + i]);
    red[d] = mx;
    __syncthreads();
#pragma unroll
    for (int st2 = 128; st2 >= 1; st2 >>= 1) {
        if (d < st2) red[d] = fmaxf(red[d], red[d + st2]);
        __syncthreads();
    }
    if (d == 0) ws[WS_MAXN] = sqrtf(red[0]);
}

// Stage [128 j][64 K] bf16 tile (16KB) cooperatively: wave w stages rows
// w*32+q*8.. via global_load_lds (linear LDS dest, PRE-SWIZZLED global src).
// Swizzle: stored[row][pg] = logical[row][pg ^ (row&7)] (16B groups).
#define STAGE(BUF, U) do {                                                      \
    const int _cc = (U) >> 2, _k0 = ((U) & 3) << 6;                             \
    const size_t _rb = (size_t)(j0 + _cc * 128 + (w << 5) + srow) * D + _k0 + (sc << 3); \
    _Pragma("unroll")                                                           \
    for (int q = 0; q < 4; ++q) {                                               \
      __builtin_amdgcn_global_load_lds(                                         \
        (const __attribute__((address_space(1))) void*)(ebf + _rb + (size_t)(q << 3) * D), \
        (__attribute__((address_space(3))) void*)&tile[BUF][((w << 5) + (q << 3)) * 64], \
        16, 0, 0);                                                              \
    } } while (0)

// Block = 32 out-rows x 2048 j. 4 waves share out-rows (bfr identical), split
// each 128-j chunk into 32-j quadrants. LDS double-buffered A-tiles; adj/sq/rv
// register-prefetched 2 units ahead.
__global__ __launch_bounds__(256, 3) void k_main(
    const float* __restrict__ adj,
    const unsigned short* __restrict__ ebf,
    const float* __restrict__ ws,
    float* __restrict__ pout,
    int* __restrict__ tixp)
{
    __shared__ unsigned short tile[2][128 * 64];   // 2 x 16KB

    const int tid = threadIdx.x;
    const int w = tid >> 6;
    const int l = tid & 63;
    const int lid = l & 15;
    const int g = l >> 4;
    const int srow = l >> 3;              // staging: row-in-slab 0..7
    const int sc = (l & 7) ^ srow;        // staging: pre-swizzled 16B group
    const int panel = blockIdx.x >> 2;    // 256 panels
    const int js = blockIdx.x & 3;
    const int row0 = panel * ROWS;
    const int j0 = js * JSPAN;

    const float* sq = ws + WS_SQ;
    const float* rinv = ws + WS_RINV;

    // persistent out-row fragments (same for all waves)
    bf16x8 bfr[2][8];
    float rvr[2];
    int r_[2];
#pragma unroll
    for (int nf = 0; nf < 2; ++nf) {
        int r = row0 + nf * 16 + lid;
        r_[nf] = r;
        rvr[nf] = rinv[r];
#pragma unroll
        for (int ks = 0; ks < 8; ++ks)
            bfr[nf][ks] = *(const bf16x8*)(ebf + (size_t)r * D + ks * 32 + g * 8);
    }

    float deg[2] = {0.f, 0.f}, pot[2] = {0.f, 0.f};
    float sl[2] = {0.f, 0.f}, st[2] = {0.f, 0.f};
    float tv[2][5]; int tix[2][5];
#pragma unroll
    for (int nf = 0; nf < 2; ++nf)
#pragma unroll
        for (int s2 = 0; s2 < 5; ++s2) { tv[nf][s2] = 1e30f; tix[nf][s2] = N; }

    f32x4 acc[2][2];
#pragma unroll
    for (int nf = 0; nf < 2; ++nf)
#pragma unroll
        for (int mf = 0; mf < 2; ++mf) acc[nf][mf] = (f32x4){0.f, 0.f, 0.f, 0.f};
    f32x4 advA[2][2], sqv[2], rvv[2];

    STAGE(0, 0);
    __syncthreads();

#pragma unroll 1
    for (int uu = 0; uu < NU; uu += 4) {
#pragma unroll
        for (int h = 0; h < 4; ++h) {
            const int u = uu + h;
            const int cur = u & 1;
            if (u + 1 < NU) STAGE(cur ^ 1, u + 1);
            if (h == 1) {
                // prefetch j-side stats + adj for this chunk's EPI (used at h==3)
                const int jj = j0 + (uu >> 2) * 128 + (w << 5);
#pragma unroll
                for (int mf = 0; mf < 2; ++mf) {
                    sqv[mf] = *(const f32x4*)(sq + jj + mf * 16 + g * 4);
                    rvv[mf] = *(const f32x4*)(rinv + jj + mf * 16 + g * 4);
                }
#pragma unroll
                for (int nf = 0; nf < 2; ++nf)
#pragma unroll
                    for (int mf = 0; mf < 2; ++mf)
                        advA[nf][mf] = __builtin_nontemporal_load(
                            (const f32x4*)(adj + (size_t)r_[nf] * N + jj + mf * 16 + g * 4));
            }
            // compute unit u: 2 K-sub-slices of 32, 8 MFMAs
#pragma unroll
            for (int ksl = 0; ksl < 2; ++ksl) {
                const int pg = ((ksl << 2) + g) ^ (lid & 7);
                bf16x8 afr[2];
#pragma unroll
                for (int mf = 0; mf < 2; ++mf)
                    afr[mf] = *(const bf16x8*)&tile[cur][((w << 5) + (mf << 4) + lid) * 64 + (pg << 3)];
#pragma unroll
                for (int nf = 0; nf < 2; ++nf)
#pragma unroll
                    for (int mf = 0; mf < 2; ++mf)
                        acc[nf][mf] = __builtin_amdgcn_mfma_f32_16x16x32_bf16(
                            afr[mf], bfr[nf][h * 2 + ksl], acc[nf][mf], 0, 0, 0);
            }
            if (h == 3) {
                const int jj = j0 + (uu >> 2) * 128 + (w << 5);
#pragma unroll
                for (int nf = 0; nf < 2; ++nf) {
#pragma unroll
                    for (int mf = 0; mf < 2; ++mf) {
#pragma unroll
                        for (int e = 0; e < 4; ++e) {
                            const float gv = acc[nf][mf][e];
                            const float a = advA[nf][mf][e];
                            const int j = jj + mf * 16 + g * 4 + e;
                            deg[nf] += a;
                            pot[nf] = fmaf(a, gv, pot[nf]);
                            const float s = (gv * rvr[nf]) * (rvv[mf][e] * a);
                            const float ex = __expf(s);
                            sl[nf] += ex;
                            st[nf] = fmaf(ex, s, st[nf]);
                            float dp = fmaf(-2.f, gv, sqv[mf][e]);
                            dp = (j == r_[nf]) ? 1e30f : dp;
                            INS5(tv[nf], tix[nf], dp, j);
                        }
                        acc[nf][mf] = (f32x4){0.f, 0.f, 0.f, 0.f};
                    }
                }
            }
            __syncthreads();
        }
    }

    // reduce across g-lanes (xor 16, 32) sharing each out-row
#pragma unroll
    for (int nf = 0; nf < 2; ++nf) {
#pragma unroll
        for (int mk = 16; mk <= 32; mk <<= 1) {
            deg[nf] += __shfl_xor(deg[nf], mk);
            pot[nf] += __shfl_xor(pot[nf], mk);
            sl[nf] += __shfl_xor(sl[nf], mk);
            st[nf] += __shfl_xor(st[nf], mk);
            float od[5]; int oi[5];
#pragma unroll
            for (int s2 = 0; s2 < 5; ++s2) {
                od[s2] = __shfl_xor(tv[nf][s2], mk);
                oi[s2] = __shfl_xor(tix[nf][s2], mk);
            }
#pragma unroll
            for (int s2 = 0; s2 < 5; ++s2) INS5(tv[nf], tix[nf], od[s2], oi[s2]);
        }
    }

    // cross-wave merge via LDS (overlay on tile memory; tile no longer read)
    float* lds_s  = (float*)&tile[0][0];           // [4][32][4]
    float* lds_tv = lds_s + 4 * 32 * 4;            // [4][32][5]
    int*   lds_ti = (int*)(lds_tv + 4 * 32 * 5);   // [4][32][5]
#pragma unroll
    for (int nf = 0; nf < 2; ++nf) {
        if (g == 0) {
            int lr = nf * 16 + lid;
            lds_s[(w * 32 + lr) * 4 + 0] = deg[nf];
            lds_s[(w * 32 + lr) * 4 + 1] = pot[nf];
            lds_s[(w * 32 + lr) * 4 + 2] = sl[nf];
            lds_s[(w * 32 + lr) * 4 + 3] = st[nf];
#pragma unroll
            for (int s2 = 0; s2 < 5; ++s2) {
                lds_tv[(w * 32 + lr) * 5 + s2] = tv[nf][s2];
                lds_ti[(w * 32 + lr) * 5 + s2] = tix[nf][s2];
            }
        }
    }
    __syncthreads();

    if (tid < 32) {
        float dg = 0.f, pt = 0.f, ll = 0.f, tt = 0.f;
#pragma unroll
        for (int w2 = 0; w2 < 4; ++w2) {
            dg += lds_s[(w2 * 32 + tid) * 4 + 0];
            pt += lds_s[(w2 * 32 + tid) * 4 + 1];
            ll += lds_s[(w2 * 32 + tid) * 4 + 2];
            tt += lds_s[(w2 * 32 + tid) * 4 + 3];
        }
        float mtv[5]; int mti[5];
#pragma unroll
        for (int s2 = 0; s2 < 5; ++s2) {
            mtv[s2] = lds_tv[tid * 5 + s2];
            mti[s2] = lds_ti[tid * 5 + s2];
        }
#pragma unroll
        for (int w2 = 1; w2 < 4; ++w2)
#pragma unroll
            for (int s2 = 0; s2 < 5; ++s2)
                INS5(mtv, mti, lds_tv[(w2 * 32 + tid) * 5 + s2], lds_ti[(w2 * 32 + tid) * 5 + s2]);
        const int slot = js * N + row0 + tid;
        pout[slot] = dg;
        pout[4 * N + slot] = pt;
        pout[8 * N + slot] = ll;
        pout[12 * N + slot] = tt;
#pragma unroll
        for (int s2 = 0; s2 < 5; ++s2) {
            pout[16 * N + slot * 5 + s2] = mtv[s2];
            tixp[slot * 5 + s2] = mti[s2];
        }
    }
}

__global__ void k_final(const float* __restrict__ emb, const float* __restrict__ ws,
                        const int* __restrict__ tixp, float* __restrict__ out) {
    int row = blockIdx.x * 4 + (threadIdx.x >> 6);
    int lane = threadIdx.x & 63;
    const float* p0 = ws + WS_P0;

    float dg = 0.f, pt = 0.f, ll = 0.f, tt = 0.f;
#pragma unroll
    for (int js = 0; js < NJS; ++js) {
        int slot = js * N + row;
        dg += p0[slot]; pt += p0[4 * N + slot];
        ll += p0[8 * N + slot]; tt += p0[12 * N + slot];
    }

    float cd[20]; int ci[20];
#pragma unroll
    for (int js = 0; js < NJS; ++js)
#pragma unroll
        for (int s = 0; s < 5; ++s) {
            int slot = js * N + row;
            cd[js * 5 + s] = p0[16 * N + slot * 5 + s];
            ci[js * 5 + s] = tixp[slot * 5 + s];
        }
    int nb[5];
    unsigned picked = 0;
#pragma unroll
    for (int sel = 0; sel < 5; ++sel) {
        float best = 1e31f; int bi = 0, bq = 0;
#pragma unroll
        for (int q = 0; q < 20; ++q) {
            bool ok = (((picked >> q) & 1u) == 0u) && (cd[q] < best);
            best = ok ? cd[q] : best;
            bi = ok ? ci[q] : bi;
            bq = ok ? q : bq;
        }
        picked |= (1u << bq);
        nb[sel] = bi;
    }

    float4 e = *(const float4*)(emb + (size_t)row * D + lane * 4);
    float4 gm = *(const float4*)(ws + WS_GMEAN + lane * 4);
    float gx = e.x - gm.x, gy = e.y - gm.y, gz = e.z - gm.z, gw = e.w - gm.w;
    float gd = gx * gx + gy * gy + gz * gz + gw * gw;
    float ax = 0.f, ay = 0.f, az = 0.f, aw = 0.f;
#pragma unroll
    for (int t = 0; t < 5; ++t) {
        float4 nv = *(const float4*)(emb + (size_t)nb[t] * D + lane * 4);
        ax += nv.x; ay += nv.y; az += nv.z; aw += nv.w;
    }
    ax *= 0.2f; ay *= 0.2f; az *= 0.2f; aw *= 0.2f;
    float lx = e.x - ax, ly = e.y - ay, lz = e.z - az, lw = e.w - aw;
    float ld = lx * lx + ly * ly + lz * lz + lw * lw;
#pragma unroll
    for (int mk = 32; mk >= 1; mk >>= 1) {
        gd += __shfl_xor(gd, mk);
        ld += __shfl_xor(ld, mk);
    }
    if (lane == 0) {
        float sqv = ws[WS_SQ + row];
        float mn = ws[WS_MAXN];
        float ent = logf(ll) - tt / ll;
        out[row] = sqv - pt / (dg + EPSF);
        out[N + row] = (dg > 0.f) ? ent : 0.f;
        out[2 * N + row] = 0.6f * sqrtf(gd) + 0.4f * sqrtf(ld);
        out[3 * N + row] = 0.5f * (dg / (8191.0f + EPSF)) + 0.5f * (sqrtf(sqv) / (mn + EPSF));
    }
}

extern "C" void kernel_launch(void* const* d_in, const int* in_sizes, int n_in,
                              void* d_out, int out_size, void* d_ws, size_t ws_size,
                              hipStream_t stream) {
    const float* emb = (const float*)d_in[0];
    const float* adj = (const float*)d_in[1];
    float* out = (float*)d_out;
    float* ws = (float*)d_ws;
    unsigned short* ebf = (unsigned short*)(ws + WS_EBF);

    k_prep<<<2304, 256, 0, stream>>>(emb, ws, ebf);
    k_colred<<<1, 256, 0, stream>>>(ws);
    k_main<<<1024, 256, 0, stream>>>(adj, ebf, ws, ws + WS_P0, (int*)(ws + WS_TIX));
    k_final<<<N / 4, 256, 0, stream>>>(emb, ws, (const int*)(ws + WS_TIX), out);
}